// Round 4
// baseline (388.540 us; speedup 1.0000x reference)
//
#include <hip/hip_runtime.h>
#include <stdint.h>

typedef __bf16 bf16_t;
typedef bf16_t bf16x8 __attribute__((ext_vector_type(8)));
typedef float f32x4 __attribute__((ext_vector_type(4)));

// ---------- helpers ----------

__device__ __forceinline__ uint16_t f2bf(float f) {
    uint32_t u = __float_as_uint(f);
    u += 0x7FFFu + ((u >> 16) & 1u);   // RNE
    return (uint16_t)(u >> 16);
}

__device__ __forceinline__ f32x4 mfma16(bf16x8 a, bf16x8 b, f32x4 c) {
    return __builtin_amdgcn_mfma_f32_16x16x32_bf16(a, b, c, 0, 0, 0);
}

// read one 16B MFMA fragment from a [rows][64] bf16 LDS tile with XOR swizzle
__device__ __forceinline__ bf16x8 lds_frag(const uint16_t* smem, int row, int kbyte) {
    int off = row * 128 + (kbyte ^ ((row & 7) << 4));
    return __builtin_bit_cast(bf16x8,
        *reinterpret_cast<const uint4*>(reinterpret_cast<const char*>(smem) + off));
}

// global -> regs (issue early), regs -> LDS swizzled (write late)  [T14 split]
template <int ROWS>
__device__ __forceinline__ void load_regs(uint4* r, const uint16_t* src,
                                          int src_stride, int tid) {
    constexpr int PER = ROWS * 8 / 256;
#pragma unroll
    for (int i = 0; i < PER; ++i) {
        int c = tid + i * 256;
        int row = c >> 3, cc = c & 7;
        r[i] = *reinterpret_cast<const uint4*>(src + (size_t)row * src_stride + cc * 8);
    }
}
template <int ROWS>
__device__ __forceinline__ void write_lds(uint16_t* lds, const uint4* r, int tid) {
    constexpr int PER = ROWS * 8 / 256;
#pragma unroll
    for (int i = 0; i < PER; ++i) {
        int c = tid + i * 256;
        int row = c >> 3, cc = c & 7;
        int off = row * 128 + ((cc * 16) ^ ((row & 7) << 4));
        *reinterpret_cast<uint4*>(reinterpret_cast<char*>(lds) + off) = r[i];
    }
}

// ---------- kernel 0: adj dtype detect ----------
// mode 0: int32 {0,1}; mode 1: float32 {0.0,1.0}; mode 2: bytes
__global__ void detect_kernel(const unsigned int* __restrict__ adj, int* __restrict__ flag) {
    __shared__ int notint, notf32;
    if (threadIdx.x == 0) { notint = 0; notf32 = 0; }
    __syncthreads();
    int ni = 0, nf = 0;
    for (int i = threadIdx.x; i < 4096; i += 256) {
        unsigned v = adj[i];
        if (v > 1u) ni = 1;
        if (v != 0u && v != 0x3f800000u) nf = 1;
    }
    if (ni) notint = 1;
    if (nf) notf32 = 1;
    __syncthreads();
    if (threadIdx.x == 0) *flag = notint ? (notf32 ? 2 : 1) : 0;
}

// ---------- kernel 0b: pack adj into bitmask [512 rows][8 x uint64] ----------
__global__ void pack_kernel(const void* __restrict__ adj, const int* __restrict__ flag,
                            uint64_t* __restrict__ bits) {
    int idx = blockIdx.x * 256 + threadIdx.x;   // 4096 words
    int row = idx >> 3, w = idx & 7;
    int mode = *flag;
    uint64_t m = 0;
    if (mode == 0) {
        const int* a = (const int*)adj + row * 512 + w * 64;
#pragma unroll 8
        for (int b = 0; b < 64; ++b) m |= (uint64_t)(a[b] != 0) << b;
    } else if (mode == 1) {
        const float* a = (const float*)adj + row * 512 + w * 64;
#pragma unroll 8
        for (int b = 0; b < 64; ++b) m |= (uint64_t)(a[b] != 0.0f) << b;
    } else {
        const unsigned char* a = (const unsigned char*)adj + row * 512 + w * 64;
#pragma unroll 8
        for (int b = 0; b < 64; ++b) m |= (uint64_t)(a[b] != 0) << b;
    }
    bits[idx] = m;
}

// ---------- kernel 1: fp32 -> bf16 convert (x + 4 weights) ----------
__global__ void convert_kernel(const float* __restrict__ x, const float* __restrict__ wq,
                               const float* __restrict__ wk, const float* __restrict__ wv,
                               const float* __restrict__ wo,
                               uint16_t* __restrict__ xb, uint16_t* __restrict__ wqb,
                               uint16_t* __restrict__ wkb, uint16_t* __restrict__ wvb,
                               uint16_t* __restrict__ wob) {
    int i = blockIdx.x * 256 + threadIdx.x;   // float4 index
    const float* src; uint16_t* dst; int idx;
    if (i < 2097152) { src = x; dst = xb; idx = i; }
    else {
        int wi = i - 2097152;
        int which = wi >> 16; idx = wi & 65535;
        src = which == 0 ? wq : which == 1 ? wk : which == 2 ? wv : wo;
        dst = which == 0 ? wqb : which == 1 ? wkb : which == 2 ? wvb : wob;
    }
    float4 v = reinterpret_cast<const float4*>(src)[idx];
    ushort4 o;
    o.x = f2bf(v.x); o.y = f2bf(v.y); o.z = f2bf(v.z); o.w = f2bf(v.w);
    reinterpret_cast<ushort4*>(dst)[idx] = o;
}

// ---------- GEMM template (2-phase reg-prefetch pipeline) ----------
// C[m][c] = sum_k A[m][k] * B[c][k]  (+bias)   A:[M][512] bf16, B:[512][512] bf16
// MODE 0: QKV -> q (pre-scaled by 1/8) / k as [B,H,N,64] bf16, v transposed [B,H,64,N]
// MODE 1: out projection -> fp32 [M][512] + bias
template <int MODE>
__launch_bounds__(256)
__global__ void gemm_kernel(const uint16_t* __restrict__ A,
                            const uint16_t* __restrict__ B0, const uint16_t* __restrict__ B1,
                            const uint16_t* __restrict__ B2,
                            const float* __restrict__ bias0, const float* __restrict__ bias1,
                            const float* __restrict__ bias2,
                            uint16_t* __restrict__ qws, uint16_t* __restrict__ kws,
                            uint16_t* __restrict__ vws, float* __restrict__ outf) {
    __shared__ uint16_t As[128 * 64];
    __shared__ uint16_t Bs[128 * 64];
    const int tid  = threadIdx.x;
    const int lane = tid & 63;
    const int wid  = tid >> 6;
    const int wm   = wid >> 1, wn = wid & 1;
    const int m0   = blockIdx.y * 128;
    const int n0   = blockIdx.x * 128;
    const int sel  = n0 >> 9;
    const int nw   = n0 & 511;
    const uint16_t* Bsrc = (MODE == 0) ? (sel == 0 ? B0 : sel == 1 ? B1 : B2) : B0;
    const int fr = lane & 15, fq = lane >> 4;

    f32x4 acc[4][4];
#pragma unroll
    for (int a = 0; a < 4; ++a)
#pragma unroll
        for (int b = 0; b < 4; ++b) acc[a][b] = (f32x4){0.f, 0.f, 0.f, 0.f};

    uint4 apre[4], bpre[4];
    load_regs<128>(apre, A + (size_t)m0 * 512, 512, tid);
    load_regs<128>(bpre, Bsrc + (size_t)nw * 512, 512, tid);

    for (int k0 = 0; k0 < 512; k0 += 64) {
        __syncthreads();
        write_lds<128>(As, apre, tid);
        write_lds<128>(Bs, bpre, tid);
        if (k0 < 448) {
            load_regs<128>(apre, A + (size_t)m0 * 512 + k0 + 64, 512, tid);
            load_regs<128>(bpre, Bsrc + (size_t)nw * 512 + k0 + 64, 512, tid);
        }
        __syncthreads();
#pragma unroll
        for (int ks = 0; ks < 2; ++ks) {
            int kb = ks * 64 + fq * 16;
            bf16x8 af[4], bfr[4];
#pragma unroll
            for (int i = 0; i < 4; ++i) af[i]  = lds_frag(As, wm * 64 + i * 16 + fr, kb);
#pragma unroll
            for (int i = 0; i < 4; ++i) bfr[i] = lds_frag(Bs, wn * 64 + i * 16 + fr, kb);
#pragma unroll
            for (int mf = 0; mf < 4; ++mf)
#pragma unroll
                for (int nf = 0; nf < 4; ++nf)
                    acc[mf][nf] = mfma16(af[mf], bfr[nf], acc[mf][nf]);
        }
    }

    if (MODE == 0) {
        const float* bias = sel == 0 ? bias0 : sel == 1 ? bias1 : bias2;
        const float sc = (sel == 0) ? 0.125f : 1.0f;   // fold 1/sqrt(DH) into q
#pragma unroll
        for (int nf = 0; nf < 4; ++nf) {
            int c  = nw + wn * 64 + nf * 16 + fr;   // col within this weight [0,512)
            float bv = bias[c];
            int h = c >> 6, dh = c & 63;
#pragma unroll
            for (int mf = 0; mf < 4; ++mf) {
                int mbase = m0 + wm * 64 + mf * 16 + fq * 4;
                int b  = mbase >> 9;
                int ns = mbase & 511;
                if (sel < 2) {
                    uint16_t* dst = (sel == 0 ? qws : kws);
                    size_t base = ((size_t)(b * 8 + h) * 512) * 64;
#pragma unroll
                    for (int j = 0; j < 4; ++j)
                        dst[base + (size_t)(ns + j) * 64 + dh] = f2bf((acc[mf][nf][j] + bv) * sc);
                } else {
                    ushort4 pk;
                    pk.x = f2bf(acc[mf][nf][0] + bv);
                    pk.y = f2bf(acc[mf][nf][1] + bv);
                    pk.z = f2bf(acc[mf][nf][2] + bv);
                    pk.w = f2bf(acc[mf][nf][3] + bv);
                    *reinterpret_cast<ushort4*>(
                        &vws[((size_t)(b * 8 + h) * 64 + dh) * 512 + ns]) = pk;
                }
            }
        }
    } else {
#pragma unroll
        for (int nf = 0; nf < 4; ++nf) {
            int c = n0 + wn * 64 + nf * 16 + fr;
            float bv = bias0[c];
#pragma unroll
            for (int mf = 0; mf < 4; ++mf) {
                int mbase = m0 + wm * 64 + mf * 16 + fq * 4;
#pragma unroll
                for (int j = 0; j < 4; ++j)
                    outf[(size_t)(mbase + j) * 512 + c] = acc[mf][nf][j] + bv;
            }
        }
    }
}

// ---------- kernel 3: masked flash attention (2-phase pipeline + bitmask) ----------
// grid: B*H*8 blocks; 4 waves, each owns 16 q-rows of a 64-row q-tile
__launch_bounds__(256)
__global__ void attn_kernel(const uint16_t* __restrict__ qws, const uint16_t* __restrict__ kws,
                            const uint16_t* __restrict__ vws,
                            const uint64_t* __restrict__ adjbits, uint16_t* __restrict__ ows) {
    __shared__ uint16_t Ks[64 * 64];
    __shared__ uint16_t Vs[64 * 64];   // V^T tile: rows = d, cols = kv
    __shared__ uint16_t Ps[4 * 16 * 64];
    __shared__ uint64_t Ab[64 * 8];    // this q-tile's mask bits
    const int tid = threadIdx.x, lane = tid & 63, w = tid >> 6;
    const int bx = blockIdx.x;
    const int qt = bx & 7, h = (bx >> 3) & 7, b = bx >> 6;
    const size_t qk_head = (size_t)(b * 8 + h) * 512 * 64;
    const size_t v_head  = (size_t)(b * 8 + h) * 64 * 512;
    const int fr = lane & 15, fq = lane >> 4;
    const int qr0 = qt * 64 + w * 16;

    // stage this q-tile's adj bits (4 KB)
    Ab[tid]       = adjbits[(size_t)qt * 512 + tid];
    Ab[tid + 256] = adjbits[(size_t)qt * 512 + tid + 256];

    // Q fragments (q pre-scaled by 1/8 in the QKV GEMM epilogue)
    bf16x8 aq[2];
#pragma unroll
    for (int ks = 0; ks < 2; ++ks)
        aq[ks] = __builtin_bit_cast(bf16x8,
            *reinterpret_cast<const uint4*>(qws + qk_head + (size_t)(qr0 + fr) * 64 + ks * 32 + fq * 8));

    float mrun[4], lsum[4];
    f32x4 oacc[4];
#pragma unroll
    for (int j = 0; j < 4; ++j) { mrun[j] = -1e30f; lsum[j] = 0.f; }
#pragma unroll
    for (int nf = 0; nf < 4; ++nf) oacc[nf] = (f32x4){0.f, 0.f, 0.f, 0.f};

    const float LOG2E = 1.4426950408889634f;

    // prefetch tile 0 into regs
    uint4 kreg[2], vreg[2];
    load_regs<64>(kreg, kws + qk_head, 64, tid);
    load_regs<64>(vreg, vws + v_head, 512, tid);

    for (int kt = 0; kt < 8; ++kt) {
        __syncthreads();                    // all waves done reading previous tile's LDS
        write_lds<64>(Ks, kreg, tid);
        write_lds<64>(Vs, vreg, tid);
        if (kt < 7) {                       // issue next-tile loads; land under this tile's compute
            load_regs<64>(kreg, kws + qk_head + (size_t)(kt + 1) * 64 * 64, 64, tid);
            load_regs<64>(vreg, vws + v_head + (size_t)(kt + 1) * 64, 512, tid);
        }
        __syncthreads();                    // LDS writes visible

        // S = Q K^T
        f32x4 sacc[4];
#pragma unroll
        for (int nf = 0; nf < 4; ++nf) sacc[nf] = (f32x4){0.f, 0.f, 0.f, 0.f};
        __builtin_amdgcn_s_setprio(1);
#pragma unroll
        for (int ks = 0; ks < 2; ++ks) {
            int kb = ks * 64 + fq * 16;
#pragma unroll
            for (int nf = 0; nf < 4; ++nf) {
                bf16x8 bk = lds_frag(Ks, nf * 16 + fr, kb);
                sacc[nf] = mfma16(aq[ks], bk, sacc[nf]);
            }
        }
        __builtin_amdgcn_s_setprio(0);

        // mask from LDS bitset (scale already folded into q)
        float s[4][4];
#pragma unroll
        for (int j = 0; j < 4; ++j) {
            uint64_t m = Ab[(w * 16 + fq * 4 + j) * 8 + kt];
#pragma unroll
            for (int nf = 0; nf < 4; ++nf)
                s[nf][j] = ((m >> (nf * 16 + fr)) & 1) ? sacc[nf][j] : -1e30f;
        }

        // online softmax update
        float fsc[4];
#pragma unroll
        for (int j = 0; j < 4; ++j) {
            float t = fmaxf(fmaxf(s[0][j], s[1][j]), fmaxf(s[2][j], s[3][j]));
            t = fmaxf(t, __shfl_xor(t, 1));
            t = fmaxf(t, __shfl_xor(t, 2));
            t = fmaxf(t, __shfl_xor(t, 4));
            t = fmaxf(t, __shfl_xor(t, 8));
            float mn = fmaxf(mrun[j], t);
            fsc[j] = exp2f((mrun[j] - mn) * LOG2E);
            mrun[j] = mn;
        }
        float rs[4] = {0.f, 0.f, 0.f, 0.f};
#pragma unroll
        for (int nf = 0; nf < 4; ++nf)
#pragma unroll
            for (int j = 0; j < 4; ++j) {
                float p = exp2f((s[nf][j] - mrun[j]) * LOG2E);
                s[nf][j] = p;
                rs[j] += p;
            }
#pragma unroll
        for (int j = 0; j < 4; ++j) {
            float r = rs[j];
            r += __shfl_xor(r, 1);
            r += __shfl_xor(r, 2);
            r += __shfl_xor(r, 4);
            r += __shfl_xor(r, 8);
            lsum[j] = lsum[j] * fsc[j] + r;
        }
#pragma unroll
        for (int nf = 0; nf < 4; ++nf)
#pragma unroll
            for (int j = 0; j < 4; ++j) oacc[nf][j] *= fsc[j];

        // P -> LDS (per-wave region, swizzled; same-wave read, no barrier needed)
        uint16_t* pw = Ps + w * 16 * 64;
#pragma unroll
        for (int nf = 0; nf < 4; ++nf)
#pragma unroll
            for (int j = 0; j < 4; ++j) {
                int rp = fq * 4 + j, cp = nf * 16 + fr;
                int off = rp * 128 + ((cp * 2) ^ ((rp & 7) << 4));
                *reinterpret_cast<uint16_t*>(reinterpret_cast<char*>(pw) + off) = f2bf(s[nf][j]);
            }

        // O += P V
        __builtin_amdgcn_s_setprio(1);
#pragma unroll
        for (int ks = 0; ks < 2; ++ks) {
            int kb = ks * 64 + fq * 16;
            bf16x8 ap = lds_frag(pw, fr, kb);
#pragma unroll
            for (int nf = 0; nf < 4; ++nf) {
                bf16x8 bv = lds_frag(Vs, nf * 16 + fr, kb);
                oacc[nf] = mfma16(ap, bv, oacc[nf]);
            }
        }
        __builtin_amdgcn_s_setprio(0);
    }

    // epilogue: divide and store o [B,N,H,64] bf16
#pragma unroll
    for (int nf = 0; nf < 4; ++nf) {
        int d = nf * 16 + fr;
#pragma unroll
        for (int j = 0; j < 4; ++j) {
            int n = qt * 64 + w * 16 + fq * 4 + j;
            float v = oacc[nf][j] / lsum[j];
            ows[((size_t)(b * 512 + n) * 8 + h) * 64 + d] = f2bf(v);
        }
    }
}

// ---------- launch ----------
extern "C" void kernel_launch(void* const* d_in, const int* in_sizes, int n_in,
                              void* d_out, int out_size, void* d_ws, size_t ws_size,
                              hipStream_t stream) {
    const float* x  = (const float*)d_in[0];
    const void*  adj = d_in[1];
    const float* Wq = (const float*)d_in[2];
    const float* Wk = (const float*)d_in[3];
    const float* Wv = (const float*)d_in[4];
    const float* bq = (const float*)d_in[5];
    const float* bk = (const float*)d_in[6];
    const float* bv = (const float*)d_in[7];
    const float* Wo = (const float*)d_in[8];
    const float* bo = (const float*)d_in[9];
    float* out = (float*)d_out;

    char* p = (char*)d_ws;
    uint16_t* xb  = (uint16_t*)p; p += (size_t)8388608 * 2;   // also reused as ows
    uint16_t* wqb = (uint16_t*)p; p += 262144 * 2;
    uint16_t* wkb = (uint16_t*)p; p += 262144 * 2;
    uint16_t* wvb = (uint16_t*)p; p += 262144 * 2;
    uint16_t* wob = (uint16_t*)p; p += 262144 * 2;
    uint16_t* qws = (uint16_t*)p; p += (size_t)8388608 * 2;
    uint16_t* kws = (uint16_t*)p; p += (size_t)8388608 * 2;
    uint16_t* vws = (uint16_t*)p; p += (size_t)8388608 * 2;
    uint64_t* adjbits = (uint64_t*)p; p += 4096 * 8;
    int* flag = (int*)p;
    uint16_t* ows = xb;   // xb dead after QKV GEMM

    detect_kernel<<<1, 256, 0, stream>>>((const unsigned int*)adj, flag);
    pack_kernel<<<16, 256, 0, stream>>>(adj, flag, adjbits);
    convert_kernel<<<9216, 256, 0, stream>>>(x, Wq, Wk, Wv, Wo, xb, wqb, wkb, wvb, wob);
    dim3 g1(12, 128);
    gemm_kernel<0><<<g1, 256, 0, stream>>>(xb, wqb, wkb, wvb, bq, bk, bv,
                                           qws, kws, vws, nullptr);
    attn_kernel<<<2048, 256, 0, stream>>>(qws, kws, vws, adjbits, ows);
    dim3 g2(4, 128);
    gemm_kernel<1><<<g2, 256, 0, stream>>>(ows, wob, wob, wob, bo, bo, bo,
                                           nullptr, nullptr, nullptr, out);
}

// Round 5
// 385.708 us; speedup vs baseline: 1.0073x; 1.0073x over previous
//
#include <hip/hip_runtime.h>
#include <stdint.h>

typedef __bf16 bf16_t;
typedef bf16_t bf16x8 __attribute__((ext_vector_type(8)));
typedef float f32x4 __attribute__((ext_vector_type(4)));

// ---------- helpers ----------

__device__ __forceinline__ uint16_t f2bf(float f) {
    uint32_t u = __float_as_uint(f);
    u += 0x7FFFu + ((u >> 16) & 1u);   // RNE
    return (uint16_t)(u >> 16);
}

__device__ __forceinline__ f32x4 mfma16(bf16x8 a, bf16x8 b, f32x4 c) {
    return __builtin_amdgcn_mfma_f32_16x16x32_bf16(a, b, c, 0, 0, 0);
}

// read one 16B MFMA fragment from a [rows][64] bf16 LDS tile with XOR swizzle
__device__ __forceinline__ bf16x8 lds_frag(const uint16_t* smem, int row, int kbyte) {
    int off = row * 128 + (kbyte ^ ((row & 7) << 4));
    return __builtin_bit_cast(bf16x8,
        *reinterpret_cast<const uint4*>(reinterpret_cast<const char*>(smem) + off));
}

// global -> regs (issue early), regs -> LDS swizzled (write late)  [T14 split]
template <int ROWS>
__device__ __forceinline__ void load_regs(uint4* r, const uint16_t* src,
                                          int src_stride, int tid) {
    constexpr int PER = ROWS * 8 / 256;
#pragma unroll
    for (int i = 0; i < PER; ++i) {
        int c = tid + i * 256;
        int row = c >> 3, cc = c & 7;
        r[i] = *reinterpret_cast<const uint4*>(src + (size_t)row * src_stride + cc * 8);
    }
}
template <int ROWS>
__device__ __forceinline__ void write_lds(uint16_t* lds, const uint4* r, int tid) {
    constexpr int PER = ROWS * 8 / 256;
#pragma unroll
    for (int i = 0; i < PER; ++i) {
        int c = tid + i * 256;
        int row = c >> 3, cc = c & 7;
        int off = row * 128 + ((cc * 16) ^ ((row & 7) << 4));
        *reinterpret_cast<uint4*>(reinterpret_cast<char*>(lds) + off) = r[i];
    }
}

// ---------- kernel 0: adj dtype detect ----------
// mode 0: int32 {0,1}; mode 1: float32 {0.0,1.0}; mode 2: bytes
__global__ void detect_kernel(const unsigned int* __restrict__ adj, int* __restrict__ flag) {
    __shared__ int notint, notf32;
    if (threadIdx.x == 0) { notint = 0; notf32 = 0; }
    __syncthreads();
    int ni = 0, nf = 0;
    for (int i = threadIdx.x; i < 4096; i += 256) {
        unsigned v = adj[i];
        if (v > 1u) ni = 1;
        if (v != 0u && v != 0x3f800000u) nf = 1;
    }
    if (ni) notint = 1;
    if (nf) notf32 = 1;
    __syncthreads();
    if (threadIdx.x == 0) *flag = notint ? (notf32 ? 2 : 1) : 0;
}

// ---------- kernel 0b: pack adj into bitmask [512 rows][8 x uint64] ----------
__global__ void pack_kernel(const void* __restrict__ adj, const int* __restrict__ flag,
                            uint64_t* __restrict__ bits) {
    int idx = blockIdx.x * 256 + threadIdx.x;   // 4096 words
    int row = idx >> 3, w = idx & 7;
    int mode = *flag;
    uint64_t m = 0;
    if (mode == 0) {
        const int* a = (const int*)adj + row * 512 + w * 64;
#pragma unroll 8
        for (int b = 0; b < 64; ++b) m |= (uint64_t)(a[b] != 0) << b;
    } else if (mode == 1) {
        const float* a = (const float*)adj + row * 512 + w * 64;
#pragma unroll 8
        for (int b = 0; b < 64; ++b) m |= (uint64_t)(a[b] != 0.0f) << b;
    } else {
        const unsigned char* a = (const unsigned char*)adj + row * 512 + w * 64;
#pragma unroll 8
        for (int b = 0; b < 64; ++b) m |= (uint64_t)(a[b] != 0) << b;
    }
    bits[idx] = m;
}

// ---------- kernel 1: fp32 -> bf16 convert (x + 4 weights) ----------
__global__ void convert_kernel(const float* __restrict__ x, const float* __restrict__ wq,
                               const float* __restrict__ wk, const float* __restrict__ wv,
                               const float* __restrict__ wo,
                               uint16_t* __restrict__ xb, uint16_t* __restrict__ wqb,
                               uint16_t* __restrict__ wkb, uint16_t* __restrict__ wvb,
                               uint16_t* __restrict__ wob) {
    int i = blockIdx.x * 256 + threadIdx.x;   // float4 index
    const float* src; uint16_t* dst; int idx;
    if (i < 2097152) { src = x; dst = xb; idx = i; }
    else {
        int wi = i - 2097152;
        int which = wi >> 16; idx = wi & 65535;
        src = which == 0 ? wq : which == 1 ? wk : which == 2 ? wv : wo;
        dst = which == 0 ? wqb : which == 1 ? wkb : which == 2 ? wvb : wob;
    }
    float4 v = reinterpret_cast<const float4*>(src)[idx];
    ushort4 o;
    o.x = f2bf(v.x); o.y = f2bf(v.y); o.z = f2bf(v.z); o.w = f2bf(v.w);
    reinterpret_cast<ushort4*>(dst)[idx] = o;
}

// ---------- GEMM template (2-phase reg-prefetch + LDS-transpose epilogue) ----------
// C[m][c] = sum_k A[m][k] * B[c][k]  (+bias)   A:[M][512] bf16, B:[512][512] bf16
// MODE 0: QKV -> q (pre-scaled by 1/8) / k as [B,H,N,64] bf16, v transposed [B,H,64,N]
// MODE 1: out projection -> fp32 [M][512] + bias
template <int MODE>
__launch_bounds__(256)
__global__ void gemm_kernel(const uint16_t* __restrict__ A,
                            const uint16_t* __restrict__ B0, const uint16_t* __restrict__ B1,
                            const uint16_t* __restrict__ B2,
                            const float* __restrict__ bias0, const float* __restrict__ bias1,
                            const float* __restrict__ bias2,
                            uint16_t* __restrict__ qws, uint16_t* __restrict__ kws,
                            uint16_t* __restrict__ vws, float* __restrict__ outf) {
    __shared__ uint16_t smem[128 * 128];     // K-loop: As|Bs; epilogue: 128x128 C tile
    uint16_t* As = smem;
    uint16_t* Bs = smem + 128 * 64;
    const int tid  = threadIdx.x;
    const int lane = tid & 63;
    const int wid  = tid >> 6;
    const int wm   = wid >> 1, wn = wid & 1;
    const int m0   = blockIdx.y * 128;
    const int n0   = blockIdx.x * 128;
    const int sel  = n0 >> 9;
    const int nw   = n0 & 511;
    const uint16_t* Bsrc = (MODE == 0) ? (sel == 0 ? B0 : sel == 1 ? B1 : B2) : B0;
    const int fr = lane & 15, fq = lane >> 4;

    f32x4 acc[4][4];
#pragma unroll
    for (int a = 0; a < 4; ++a)
#pragma unroll
        for (int b = 0; b < 4; ++b) acc[a][b] = (f32x4){0.f, 0.f, 0.f, 0.f};

    uint4 apre[4], bpre[4];
    load_regs<128>(apre, A + (size_t)m0 * 512, 512, tid);
    load_regs<128>(bpre, Bsrc + (size_t)nw * 512, 512, tid);

    for (int k0 = 0; k0 < 512; k0 += 64) {
        __syncthreads();
        write_lds<128>(As, apre, tid);
        write_lds<128>(Bs, bpre, tid);
        if (k0 < 448) {
            load_regs<128>(apre, A + (size_t)m0 * 512 + k0 + 64, 512, tid);
            load_regs<128>(bpre, Bsrc + (size_t)nw * 512 + k0 + 64, 512, tid);
        }
        __syncthreads();
#pragma unroll
        for (int ks = 0; ks < 2; ++ks) {
            int kb = ks * 64 + fq * 16;
            bf16x8 af[4], bfr[4];
#pragma unroll
            for (int i = 0; i < 4; ++i) af[i]  = lds_frag(As, wm * 64 + i * 16 + fr, kb);
#pragma unroll
            for (int i = 0; i < 4; ++i) bfr[i] = lds_frag(Bs, wn * 64 + i * 16 + fr, kb);
#pragma unroll
            for (int mf = 0; mf < 4; ++mf)
#pragma unroll
                for (int nf = 0; nf < 4; ++nf)
                    acc[mf][nf] = mfma16(af[mf], bfr[nf], acc[mf][nf]);
        }
    }

    if (MODE == 0) {
        const float* bias = sel == 0 ? bias0 : sel == 1 ? bias1 : bias2;
        const float sc = (sel == 0) ? 0.125f : 1.0f;   // fold 1/sqrt(DH) into q
        const int b  = m0 >> 9;        // batch (tile never spans batches: 512%128==0)
        const int ns = m0 & 511;       // n-offset within batch
        const int h0 = nw >> 6;        // head for tile-cols 0..63; h0+1 for 64..127
        char* sm = reinterpret_cast<char*>(smem);
        __syncthreads();               // K-loop LDS reads done before overwrite

        if (sel < 2) {
            // ---- dump acc -> LDS [m][c] (bf16, XOR-swizzled), b32-packed ----
#pragma unroll
            for (int nf = 0; nf < 4; ++nf) {
                int c = wn * 64 + nf * 16 + fr;
                float bv = bias[nw + c];
#pragma unroll
                for (int mf = 0; mf < 4; ++mf) {
#pragma unroll
                    for (int j = 0; j < 4; ++j) {
                        int m = wm * 64 + mf * 16 + fq * 4 + j;
                        uint32_t u = f2bf((acc[mf][nf][j] + bv) * sc);
                        uint32_t partner = __shfl_xor((int)u, 1);
                        if ((fr & 1) == 0) {
                            uint32_t word = u | (partner << 16);
                            int off = m * 256 + (((c & ~1) * 2) ^ ((m & 7) << 4));
                            *reinterpret_cast<uint32_t*>(sm + off) = word;
                        }
                    }
                }
            }
            __syncthreads();
            // ---- read back rows, store coalesced to [B,H,N,64] ----
            uint16_t* dst = (sel == 0) ? qws : kws;
#pragma unroll
            for (int pass = 0; pass < 8; ++pass) {
                int idx = pass * 256 + tid;          // 2048 16B chunks
                int m = idx >> 4, cchunk = idx & 15;
                int off = m * 256 + ((cchunk * 16) ^ ((m & 7) << 4));
                uint4 v = *reinterpret_cast<const uint4*>(sm + off);
                int h = h0 + (cchunk >> 3), dh = (cchunk & 7) * 8;
                *reinterpret_cast<uint4*>(
                    dst + ((size_t)((b * 8 + h) * 512) + ns + m) * 64 + dh) = v;
            }
        } else {
            // ---- dump acc -> LDS transposed [c][m] (bf16, XOR-swizzled), 8B-packed ----
#pragma unroll
            for (int nf = 0; nf < 4; ++nf) {
                int c = wn * 64 + nf * 16 + fr;
                float bv = bias[nw + c];
#pragma unroll
                for (int mf = 0; mf < 4; ++mf) {
                    int m = wm * 64 + mf * 16 + fq * 4;   // j-run of 4, 8B aligned
                    uint16_t p0 = f2bf(acc[mf][nf][0] + bv);
                    uint16_t p1 = f2bf(acc[mf][nf][1] + bv);
                    uint16_t p2 = f2bf(acc[mf][nf][2] + bv);
                    uint16_t p3 = f2bf(acc[mf][nf][3] + bv);
                    uint64_t pk = (uint64_t)p0 | ((uint64_t)p1 << 16) |
                                  ((uint64_t)p2 << 32) | ((uint64_t)p3 << 48);
                    int off = c * 256 + ((m * 2) ^ ((c & 7) << 4));
                    *reinterpret_cast<uint64_t*>(sm + off) = pk;
                }
            }
            __syncthreads();
            // ---- read back rows of V^T, store coalesced to [B,H,64,N] ----
#pragma unroll
            for (int pass = 0; pass < 8; ++pass) {
                int idx = pass * 256 + tid;          // 2048 16B chunks
                int c = idx >> 4, mchunk = idx & 15;
                int off = c * 256 + ((mchunk * 16) ^ ((c & 7) << 4));
                uint4 v = *reinterpret_cast<const uint4*>(sm + off);
                int h = h0 + (c >> 6), dh = c & 63;
                *reinterpret_cast<uint4*>(
                    vws + ((size_t)((b * 8 + h) * 64) + dh) * 512 + ns + mchunk * 8) = v;
            }
        }
    } else {
#pragma unroll
        for (int nf = 0; nf < 4; ++nf) {
            int c = n0 + wn * 64 + nf * 16 + fr;
            float bv = bias0[c];
#pragma unroll
            for (int mf = 0; mf < 4; ++mf) {
                int mbase = m0 + wm * 64 + mf * 16 + fq * 4;
#pragma unroll
                for (int j = 0; j < 4; ++j)
                    outf[(size_t)(mbase + j) * 512 + c] = acc[mf][nf][j] + bv;
            }
        }
    }
}

// ---------- kernel 3: masked flash attention (2-phase pipeline + bitmask) ----------
// grid: B*H*8 blocks; 4 waves, each owns 16 q-rows of a 64-row q-tile
__launch_bounds__(256)
__global__ void attn_kernel(const uint16_t* __restrict__ qws, const uint16_t* __restrict__ kws,
                            const uint16_t* __restrict__ vws,
                            const uint64_t* __restrict__ adjbits, uint16_t* __restrict__ ows) {
    __shared__ uint16_t Ks[64 * 64];
    __shared__ uint16_t Vs[64 * 64];   // V^T tile: rows = d, cols = kv
    __shared__ uint16_t Ps[4 * 16 * 64];
    __shared__ uint64_t Ab[64 * 8];    // this q-tile's mask bits
    const int tid = threadIdx.x, lane = tid & 63, w = tid >> 6;
    const int bx = blockIdx.x;
    const int qt = bx & 7, h = (bx >> 3) & 7, b = bx >> 6;
    const size_t qk_head = (size_t)(b * 8 + h) * 512 * 64;
    const size_t v_head  = (size_t)(b * 8 + h) * 64 * 512;
    const int fr = lane & 15, fq = lane >> 4;
    const int qr0 = qt * 64 + w * 16;

    // stage this q-tile's adj bits (4 KB)
    Ab[tid]       = adjbits[(size_t)qt * 512 + tid];
    Ab[tid + 256] = adjbits[(size_t)qt * 512 + tid + 256];

    // Q fragments (q pre-scaled by 1/8 in the QKV GEMM epilogue)
    bf16x8 aq[2];
#pragma unroll
    for (int ks = 0; ks < 2; ++ks)
        aq[ks] = __builtin_bit_cast(bf16x8,
            *reinterpret_cast<const uint4*>(qws + qk_head + (size_t)(qr0 + fr) * 64 + ks * 32 + fq * 8));

    float mrun[4], lsum[4];
    f32x4 oacc[4];
#pragma unroll
    for (int j = 0; j < 4; ++j) { mrun[j] = -1e30f; lsum[j] = 0.f; }
#pragma unroll
    for (int nf = 0; nf < 4; ++nf) oacc[nf] = (f32x4){0.f, 0.f, 0.f, 0.f};

    const float LOG2E = 1.4426950408889634f;

    // prefetch tile 0 into regs
    uint4 kreg[2], vreg[2];
    load_regs<64>(kreg, kws + qk_head, 64, tid);
    load_regs<64>(vreg, vws + v_head, 512, tid);

    for (int kt = 0; kt < 8; ++kt) {
        __syncthreads();                    // all waves done reading previous tile's LDS
        write_lds<64>(Ks, kreg, tid);
        write_lds<64>(Vs, vreg, tid);
        if (kt < 7) {                       // issue next-tile loads; land under this tile's compute
            load_regs<64>(kreg, kws + qk_head + (size_t)(kt + 1) * 64 * 64, 64, tid);
            load_regs<64>(vreg, vws + v_head + (size_t)(kt + 1) * 64, 512, tid);
        }
        __syncthreads();                    // LDS writes visible

        // S = Q K^T
        f32x4 sacc[4];
#pragma unroll
        for (int nf = 0; nf < 4; ++nf) sacc[nf] = (f32x4){0.f, 0.f, 0.f, 0.f};
        __builtin_amdgcn_s_setprio(1);
#pragma unroll
        for (int ks = 0; ks < 2; ++ks) {
            int kb = ks * 64 + fq * 16;
#pragma unroll
            for (int nf = 0; nf < 4; ++nf) {
                bf16x8 bk = lds_frag(Ks, nf * 16 + fr, kb);
                sacc[nf] = mfma16(aq[ks], bk, sacc[nf]);
            }
        }
        __builtin_amdgcn_s_setprio(0);

        // mask from LDS bitset (scale already folded into q)
        float s[4][4];
#pragma unroll
        for (int j = 0; j < 4; ++j) {
            uint64_t m = Ab[(w * 16 + fq * 4 + j) * 8 + kt];
#pragma unroll
            for (int nf = 0; nf < 4; ++nf)
                s[nf][j] = ((m >> (nf * 16 + fr)) & 1) ? sacc[nf][j] : -1e30f;
        }

        // online softmax update
        float fsc[4];
#pragma unroll
        for (int j = 0; j < 4; ++j) {
            float t = fmaxf(fmaxf(s[0][j], s[1][j]), fmaxf(s[2][j], s[3][j]));
            t = fmaxf(t, __shfl_xor(t, 1));
            t = fmaxf(t, __shfl_xor(t, 2));
            t = fmaxf(t, __shfl_xor(t, 4));
            t = fmaxf(t, __shfl_xor(t, 8));
            float mn = fmaxf(mrun[j], t);
            fsc[j] = exp2f((mrun[j] - mn) * LOG2E);
            mrun[j] = mn;
        }
        float rs[4] = {0.f, 0.f, 0.f, 0.f};
#pragma unroll
        for (int nf = 0; nf < 4; ++nf)
#pragma unroll
            for (int j = 0; j < 4; ++j) {
                float p = exp2f((s[nf][j] - mrun[j]) * LOG2E);
                s[nf][j] = p;
                rs[j] += p;
            }
#pragma unroll
        for (int j = 0; j < 4; ++j) {
            float r = rs[j];
            r += __shfl_xor(r, 1);
            r += __shfl_xor(r, 2);
            r += __shfl_xor(r, 4);
            r += __shfl_xor(r, 8);
            lsum[j] = lsum[j] * fsc[j] + r;
        }
#pragma unroll
        for (int nf = 0; nf < 4; ++nf)
#pragma unroll
            for (int j = 0; j < 4; ++j) oacc[nf][j] *= fsc[j];

        // P -> LDS (per-wave region, swizzled; same-wave read, no barrier needed)
        uint16_t* pw = Ps + w * 16 * 64;
#pragma unroll
        for (int nf = 0; nf < 4; ++nf)
#pragma unroll
            for (int j = 0; j < 4; ++j) {
                int rp = fq * 4 + j, cp = nf * 16 + fr;
                int off = rp * 128 + ((cp * 2) ^ ((rp & 7) << 4));
                *reinterpret_cast<uint16_t*>(reinterpret_cast<char*>(pw) + off) = f2bf(s[nf][j]);
            }

        // O += P V
        __builtin_amdgcn_s_setprio(1);
#pragma unroll
        for (int ks = 0; ks < 2; ++ks) {
            int kb = ks * 64 + fq * 16;
            bf16x8 ap = lds_frag(pw, fr, kb);
#pragma unroll
            for (int nf = 0; nf < 4; ++nf) {
                bf16x8 bv = lds_frag(Vs, nf * 16 + fr, kb);
                oacc[nf] = mfma16(ap, bv, oacc[nf]);
            }
        }
        __builtin_amdgcn_s_setprio(0);
    }

    // epilogue: divide and store o [B,N,H,64] bf16
#pragma unroll
    for (int nf = 0; nf < 4; ++nf) {
        int d = nf * 16 + fr;
#pragma unroll
        for (int j = 0; j < 4; ++j) {
            int n = qt * 64 + w * 16 + fq * 4 + j;
            float v = oacc[nf][j] / lsum[j];
            ows[((size_t)(b * 512 + n) * 8 + h) * 64 + d] = f2bf(v);
        }
    }
}

// ---------- launch ----------
extern "C" void kernel_launch(void* const* d_in, const int* in_sizes, int n_in,
                              void* d_out, int out_size, void* d_ws, size_t ws_size,
                              hipStream_t stream) {
    const float* x  = (const float*)d_in[0];
    const void*  adj = d_in[1];
    const float* Wq = (const float*)d_in[2];
    const float* Wk = (const float*)d_in[3];
    const float* Wv = (const float*)d_in[4];
    const float* bq = (const float*)d_in[5];
    const float* bk = (const float*)d_in[6];
    const float* bv = (const float*)d_in[7];
    const float* Wo = (const float*)d_in[8];
    const float* bo = (const float*)d_in[9];
    float* out = (float*)d_out;

    char* p = (char*)d_ws;
    uint16_t* xb  = (uint16_t*)p; p += (size_t)8388608 * 2;   // also reused as ows
    uint16_t* wqb = (uint16_t*)p; p += 262144 * 2;
    uint16_t* wkb = (uint16_t*)p; p += 262144 * 2;
    uint16_t* wvb = (uint16_t*)p; p += 262144 * 2;
    uint16_t* wob = (uint16_t*)p; p += 262144 * 2;
    uint16_t* qws = (uint16_t*)p; p += (size_t)8388608 * 2;
    uint16_t* kws = (uint16_t*)p; p += (size_t)8388608 * 2;
    uint16_t* vws = (uint16_t*)p; p += (size_t)8388608 * 2;
    uint64_t* adjbits = (uint64_t*)p; p += 4096 * 8;
    int* flag = (int*)p;
    uint16_t* ows = xb;   // xb dead after QKV GEMM

    detect_kernel<<<1, 256, 0, stream>>>((const unsigned int*)adj, flag);
    pack_kernel<<<16, 256, 0, stream>>>(adj, flag, adjbits);
    convert_kernel<<<9216, 256, 0, stream>>>(x, Wq, Wk, Wv, Wo, xb, wqb, wkb, wvb, wob);
    dim3 g1(12, 128);
    gemm_kernel<0><<<g1, 256, 0, stream>>>(xb, wqb, wkb, wvb, bq, bk, bv,
                                           qws, kws, vws, nullptr);
    attn_kernel<<<2048, 256, 0, stream>>>(qws, kws, vws, adjbits, ows);
    dim3 g2(4, 128);
    gemm_kernel<1><<<g2, 256, 0, stream>>>(ows, wob, wob, wob, bo, bo, bo,
                                           nullptr, nullptr, nullptr, out);
}

// Round 14
// 316.108 us; speedup vs baseline: 1.2291x; 1.2202x over previous
//
#include <hip/hip_runtime.h>
#include <stdint.h>

typedef __bf16 bf16_t;
typedef bf16_t bf16x8 __attribute__((ext_vector_type(8)));
typedef float f32x4 __attribute__((ext_vector_type(4)));

// ---------- helpers ----------

__device__ __forceinline__ uint16_t f2bf(float f) {
    uint32_t u = __float_as_uint(f);
    u += 0x7FFFu + ((u >> 16) & 1u);   // RNE
    return (uint16_t)(u >> 16);
}
__device__ __forceinline__ uint32_t pk2bf(float lo, float hi) {
    return (uint32_t)f2bf(lo) | ((uint32_t)f2bf(hi) << 16);
}

__device__ __forceinline__ f32x4 mfma16(bf16x8 a, bf16x8 b, f32x4 c) {
    return __builtin_amdgcn_mfma_f32_16x16x32_bf16(a, b, c, 0, 0, 0);
}

// read one 16B MFMA fragment from a [rows][64] bf16 LDS tile with XOR swizzle
__device__ __forceinline__ bf16x8 lds_frag(const uint16_t* smem, int row, int kbyte) {
    int off = row * 128 + (kbyte ^ ((row & 7) << 4));
    return __builtin_bit_cast(bf16x8,
        *reinterpret_cast<const uint4*>(reinterpret_cast<const char*>(smem) + off));
}

// bf16 tile staging (256 threads): global -> regs, regs -> swizzled LDS
template <int ROWS>
__device__ __forceinline__ void load_regs(uint4* r, const uint16_t* src,
                                          int src_stride, int tid) {
    constexpr int PER = ROWS * 8 / 256;
#pragma unroll
    for (int i = 0; i < PER; ++i) {
        int c = tid + i * 256;
        int row = c >> 3, cc = c & 7;
        r[i] = *reinterpret_cast<const uint4*>(src + (size_t)row * src_stride + cc * 8);
    }
}
template <int ROWS>
__device__ __forceinline__ void write_lds(uint16_t* lds, const uint4* r, int tid) {
    constexpr int PER = ROWS * 8 / 256;
#pragma unroll
    for (int i = 0; i < PER; ++i) {
        int c = tid + i * 256;
        int row = c >> 3, cc = c & 7;
        int off = row * 128 + ((cc * 16) ^ ((row & 7) << 4));
        *reinterpret_cast<uint4*>(reinterpret_cast<char*>(lds) + off) = r[i];
    }
}

// fp32 tile staging for 128-row tile (256 threads): 8 float4 per thread
__device__ __forceinline__ void load_regs_f32(float4* r, const float* src, int tid) {
#pragma unroll
    for (int i = 0; i < 4; ++i) {
        int fc = tid * 2 + i * 512;          // even float4 index
        int row = fc >> 4, cc = fc & 15;
        const float* p = src + (size_t)row * 512 + cc * 4;
        r[2 * i]     = *reinterpret_cast<const float4*>(p);
        r[2 * i + 1] = *reinterpret_cast<const float4*>(p + 4);
    }
}
__device__ __forceinline__ void write_lds_f32(uint16_t* lds, const float4* r, int tid) {
#pragma unroll
    for (int i = 0; i < 4; ++i) {
        int c = tid + i * 256;               // bf16 16B-chunk index
        int row = c >> 3, cc = c & 7;
        uint4 u;
        u.x = pk2bf(r[2 * i].x,     r[2 * i].y);
        u.y = pk2bf(r[2 * i].z,     r[2 * i].w);
        u.z = pk2bf(r[2 * i + 1].x, r[2 * i + 1].y);
        u.w = pk2bf(r[2 * i + 1].z, r[2 * i + 1].w);
        int off = row * 128 + ((cc * 16) ^ ((row & 7) << 4));
        *reinterpret_cast<uint4*>(reinterpret_cast<char*>(lds) + off) = u;
    }
}

// ---------- kernel 0: adj dtype detect ----------
__global__ void detect_kernel(const unsigned int* __restrict__ adj, int* __restrict__ flag) {
    __shared__ int notint, notf32;
    if (threadIdx.x == 0) { notint = 0; notf32 = 0; }
    __syncthreads();
    int ni = 0, nf = 0;
    for (int i = threadIdx.x; i < 4096; i += 256) {
        unsigned v = adj[i];
        if (v > 1u) ni = 1;
        if (v != 0u && v != 0x3f800000u) nf = 1;
    }
    if (ni) notint = 1;
    if (nf) notf32 = 1;
    __syncthreads();
    if (threadIdx.x == 0) *flag = notint ? (notf32 ? 2 : 1) : 0;
}

// ---------- kernel 0b: pack adj into bitmask [512 rows][8 x uint64] ----------
__global__ void pack_kernel(const void* __restrict__ adj, const int* __restrict__ flag,
                            uint64_t* __restrict__ bits) {
    int idx = blockIdx.x * 256 + threadIdx.x;   // 4096 words
    int row = idx >> 3, w = idx & 7;
    int mode = *flag;
    uint64_t m = 0;
    if (mode == 0) {
        const int* a = (const int*)adj + row * 512 + w * 64;
#pragma unroll 8
        for (int b = 0; b < 64; ++b) m |= (uint64_t)(a[b] != 0) << b;
    } else if (mode == 1) {
        const float* a = (const float*)adj + row * 512 + w * 64;
#pragma unroll 8
        for (int b = 0; b < 64; ++b) m |= (uint64_t)(a[b] != 0.0f) << b;
    } else {
        const unsigned char* a = (const unsigned char*)adj + row * 512 + w * 64;
#pragma unroll 8
        for (int b = 0; b < 64; ++b) m |= (uint64_t)(a[b] != 0) << b;
    }
    bits[idx] = m;
}

// ---------- kernel 1: fp32 -> bf16 convert (weights only now) ----------
__global__ void convert_kernel(const float* __restrict__ wq, const float* __restrict__ wk,
                               const float* __restrict__ wv, const float* __restrict__ wo,
                               uint16_t* __restrict__ wqb, uint16_t* __restrict__ wkb,
                               uint16_t* __restrict__ wvb, uint16_t* __restrict__ wob) {
    int i = blockIdx.x * 256 + threadIdx.x;   // float4 index over 4*65536
    int which = i >> 16, idx = i & 65535;
    const float* src = which == 0 ? wq : which == 1 ? wk : which == 2 ? wv : wo;
    uint16_t*    dst = which == 0 ? wqb : which == 1 ? wkb : which == 2 ? wvb : wob;
    float4 v = reinterpret_cast<const float4*>(src)[idx];
    ushort4 o;
    o.x = f2bf(v.x); o.y = f2bf(v.y); o.z = f2bf(v.z); o.w = f2bf(v.w);
    reinterpret_cast<ushort4*>(dst)[idx] = o;
}

// ---------- GEMM template (2-phase reg-prefetch + LDS-transpose epilogue) ----------
// MODE 0: A = x fp32 (convert in staging); writes q (pre-scaled 1/8), k [B,H,N,64], v^T [B,H,64,N]
// MODE 1: A = bf16 (attn out); writes fp32 [M][512] + bias
template <int MODE>
__launch_bounds__(256)
__global__ void gemm_kernel(const float* __restrict__ Af, const uint16_t* __restrict__ Ab,
                            const uint16_t* __restrict__ B0, const uint16_t* __restrict__ B1,
                            const uint16_t* __restrict__ B2,
                            const float* __restrict__ bias0, const float* __restrict__ bias1,
                            const float* __restrict__ bias2,
                            uint16_t* __restrict__ qws, uint16_t* __restrict__ kws,
                            uint16_t* __restrict__ vws, float* __restrict__ outf) {
    __shared__ uint16_t smem[128 * 128];     // K-loop: As|Bs; epilogue: 128x128 C tile
    uint16_t* As = smem;
    uint16_t* Bs = smem + 128 * 64;
    const int tid  = threadIdx.x;
    const int lane = tid & 63;
    const int wid  = tid >> 6;
    const int wm   = wid >> 1, wn = wid & 1;
    const int m0   = blockIdx.y * 128;
    const int n0   = blockIdx.x * 128;
    const int sel  = n0 >> 9;
    const int nw   = n0 & 511;
    const uint16_t* Bsrc = (MODE == 0) ? (sel == 0 ? B0 : sel == 1 ? B1 : B2) : B0;
    const int fr = lane & 15, fq = lane >> 4;

    f32x4 acc[4][4];
#pragma unroll
    for (int a = 0; a < 4; ++a)
#pragma unroll
        for (int b = 0; b < 4; ++b) acc[a][b] = (f32x4){0.f, 0.f, 0.f, 0.f};

    float4 apre_f[8];
    uint4  apre_b[4];
    uint4  bpre[4];
    if (MODE == 0) load_regs_f32(apre_f, Af + (size_t)m0 * 512, tid);
    else           load_regs<128>(apre_b, Ab + (size_t)m0 * 512, 512, tid);
    load_regs<128>(bpre, Bsrc + (size_t)nw * 512, 512, tid);

    for (int k0 = 0; k0 < 512; k0 += 64) {
        __syncthreads();
        if (MODE == 0) write_lds_f32(As, apre_f, tid);
        else           write_lds<128>(As, apre_b, tid);
        write_lds<128>(Bs, bpre, tid);
        if (k0 < 448) {
            if (MODE == 0) load_regs_f32(apre_f, Af + (size_t)m0 * 512 + k0 + 64, tid);
            else           load_regs<128>(apre_b, Ab + (size_t)m0 * 512 + k0 + 64, 512, tid);
            load_regs<128>(bpre, Bsrc + (size_t)nw * 512 + k0 + 64, 512, tid);
        }
        __syncthreads();
#pragma unroll
        for (int ks = 0; ks < 2; ++ks) {
            int kb = ks * 64 + fq * 16;
            bf16x8 af[4], bfr[4];
#pragma unroll
            for (int i = 0; i < 4; ++i) af[i]  = lds_frag(As, wm * 64 + i * 16 + fr, kb);
#pragma unroll
            for (int i = 0; i < 4; ++i) bfr[i] = lds_frag(Bs, wn * 64 + i * 16 + fr, kb);
#pragma unroll
            for (int mf = 0; mf < 4; ++mf)
#pragma unroll
                for (int nf = 0; nf < 4; ++nf)
                    acc[mf][nf] = mfma16(af[mf], bfr[nf], acc[mf][nf]);
        }
    }

    if (MODE == 0) {
        const float* bias = sel == 0 ? bias0 : sel == 1 ? bias1 : bias2;
        const float sc = (sel == 0) ? 0.125f : 1.0f;   // fold 1/sqrt(DH) into q
        const int b  = m0 >> 9;
        const int ns = m0 & 511;
        const int h0 = nw >> 6;
        char* sm = reinterpret_cast<char*>(smem);
        __syncthreads();

        if (sel < 2) {
            // acc -> LDS [m][c] bf16 swizzled, b32-packed
#pragma unroll
            for (int nf = 0; nf < 4; ++nf) {
                int c = wn * 64 + nf * 16 + fr;
                float bv = bias[nw + c];
#pragma unroll
                for (int mf = 0; mf < 4; ++mf) {
#pragma unroll
                    for (int j = 0; j < 4; ++j) {
                        int m = wm * 64 + mf * 16 + fq * 4 + j;
                        uint32_t u = f2bf((acc[mf][nf][j] + bv) * sc);
                        uint32_t partner = __shfl_xor((int)u, 1);
                        if ((fr & 1) == 0) {
                            uint32_t word = u | (partner << 16);
                            int off = m * 256 + (((c & ~1) * 2) ^ ((m & 7) << 4));
                            *reinterpret_cast<uint32_t*>(sm + off) = word;
                        }
                    }
                }
            }
            __syncthreads();
            uint16_t* dst = (sel == 0) ? qws : kws;
#pragma unroll
            for (int pass = 0; pass < 8; ++pass) {
                int idx = pass * 256 + tid;
                int m = idx >> 4, cchunk = idx & 15;
                int off = m * 256 + ((cchunk * 16) ^ ((m & 7) << 4));
                uint4 v = *reinterpret_cast<const uint4*>(sm + off);
                int h = h0 + (cchunk >> 3), dh = (cchunk & 7) * 8;
                *reinterpret_cast<uint4*>(
                    dst + ((size_t)((b * 8 + h) * 512) + ns + m) * 64 + dh) = v;
            }
        } else {
            // acc -> LDS transposed [c][m] bf16 swizzled, 8B-packed
#pragma unroll
            for (int nf = 0; nf < 4; ++nf) {
                int c = wn * 64 + nf * 16 + fr;
                float bv = bias[nw + c];
#pragma unroll
                for (int mf = 0; mf < 4; ++mf) {
                    int m = wm * 64 + mf * 16 + fq * 4;
                    uint64_t pk = (uint64_t)f2bf(acc[mf][nf][0] + bv) |
                                  ((uint64_t)f2bf(acc[mf][nf][1] + bv) << 16) |
                                  ((uint64_t)f2bf(acc[mf][nf][2] + bv) << 32) |
                                  ((uint64_t)f2bf(acc[mf][nf][3] + bv) << 48);
                    int off = c * 256 + ((m * 2) ^ ((c & 7) << 4));
                    *reinterpret_cast<uint64_t*>(sm + off) = pk;
                }
            }
            __syncthreads();
#pragma unroll
            for (int pass = 0; pass < 8; ++pass) {
                int idx = pass * 256 + tid;
                int c = idx >> 4, mchunk = idx & 15;
                int off = c * 256 + ((mchunk * 16) ^ ((c & 7) << 4));
                uint4 v = *reinterpret_cast<const uint4*>(sm + off);
                int h = h0 + (c >> 6), dh = c & 63;
                *reinterpret_cast<uint4*>(
                    vws + ((size_t)((b * 8 + h) * 64) + dh) * 512 + ns + mchunk * 8) = v;
            }
        }
    } else {
#pragma unroll
        for (int nf = 0; nf < 4; ++nf) {
            int c = n0 + wn * 64 + nf * 16 + fr;
            float bv = bias0[c];
#pragma unroll
            for (int mf = 0; mf < 4; ++mf) {
                int mbase = m0 + wm * 64 + mf * 16 + fq * 4;
#pragma unroll
                for (int j = 0; j < 4; ++j)
                    outf[(size_t)(mbase + j) * 512 + c] = acc[mf][nf][j] + bv;
            }
        }
    }
}

// ---------- kernel 3: masked flash attention, whole head per block ----------
// grid: B*H = 256 blocks; 512 threads; K + V^T resident in LDS (144 KB)
__launch_bounds__(512)
__global__ void attn_kernel(const uint16_t* __restrict__ qws, const uint16_t* __restrict__ kws,
                            const uint16_t* __restrict__ vws,
                            const uint64_t* __restrict__ adjbits, uint16_t* __restrict__ ows) {
    __shared__ uint16_t Kall[8 * 64 * 64];   // 8 kv-subtiles, swizzled [64][64]
    __shared__ uint16_t Vall[8 * 64 * 64];   // V^T: rows=d, cols=kv, per subtile
    __shared__ uint16_t Ps[8 * 16 * 64];     // per-wave P tile
    const int tid = threadIdx.x, lane = tid & 63, w = tid >> 6;
    const int bx = blockIdx.x;               // b*8 + h
    const int h = bx & 7, b = bx >> 3;
    const size_t qk_head = (size_t)bx * 512 * 64;
    const size_t v_head  = (size_t)bx * 64 * 512;
    const int fr = lane & 15, fq = lane >> 4;
    const float LOG2E = 1.4426950408889634f;

    // ---- stage all K, V^T for this head (128 KB), single barrier ----
    {
        int r = tid >> 3, cc = tid & 7;
        uint4 kr[8], vr[8];
#pragma unroll
        for (int kt = 0; kt < 8; ++kt)
            kr[kt] = *reinterpret_cast<const uint4*>(
                kws + qk_head + (size_t)(kt * 64 + r) * 64 + cc * 8);
#pragma unroll
        for (int kt = 0; kt < 8; ++kt)
            vr[kt] = *reinterpret_cast<const uint4*>(
                vws + v_head + (size_t)r * 512 + kt * 64 + cc * 8);
        int off = r * 128 + ((cc * 16) ^ ((r & 7) << 4));
#pragma unroll
        for (int kt = 0; kt < 8; ++kt) {
            *reinterpret_cast<uint4*>(reinterpret_cast<char*>(Kall + kt * 4096) + off) = kr[kt];
            *reinterpret_cast<uint4*>(reinterpret_cast<char*>(Vall + kt * 4096) + off) = vr[kt];
        }
    }

    // Q fragments for strip 0 (issued before barrier to overlap)
    bf16x8 aq0, aq1, aqn0, aqn1;
    {
        int qr0 = w * 16;
        aq0 = __builtin_bit_cast(bf16x8, *reinterpret_cast<const uint4*>(
            qws + qk_head + (size_t)(qr0 + fr) * 64 + fq * 8));
        aq1 = __builtin_bit_cast(bf16x8, *reinterpret_cast<const uint4*>(
            qws + qk_head + (size_t)(qr0 + fr) * 64 + 32 + fq * 8));
    }
    __syncthreads();   // K/V visible; no further barriers — waves independent

    uint16_t* pw = Ps + w * 16 * 64;

    for (int it = 0; it < 4; ++it) {
        const int qr0 = it * 128 + w * 16;
        const int itn = (it + 1) & 3;
        const int qrn = itn * 128 + w * 16;
        // prefetch next strip's Q (wraps at it=3; harmless)
        aqn0 = __builtin_bit_cast(bf16x8, *reinterpret_cast<const uint4*>(
            qws + qk_head + (size_t)(qrn + fr) * 64 + fq * 8));
        aqn1 = __builtin_bit_cast(bf16x8, *reinterpret_cast<const uint4*>(
            qws + qk_head + (size_t)(qrn + fr) * 64 + 32 + fq * 8));

        // adj words, double-buffered over kt
        uint64_t adjw[2][4];
#pragma unroll
        for (int j = 0; j < 4; ++j)
            adjw[0][j] = adjbits[(size_t)(qr0 + fq * 4 + j) * 8 + 0];

        float mrun[4], lsum[4];
        f32x4 oacc[4];
#pragma unroll
        for (int j = 0; j < 4; ++j) { mrun[j] = -1e30f; lsum[j] = 0.f; }
#pragma unroll
        for (int nf = 0; nf < 4; ++nf) oacc[nf] = (f32x4){0.f, 0.f, 0.f, 0.f};

#pragma unroll
        for (int kt = 0; kt < 8; ++kt) {
            if (kt < 7) {
#pragma unroll
                for (int j = 0; j < 4; ++j)
                    adjw[(kt + 1) & 1][j] = adjbits[(size_t)(qr0 + fq * 4 + j) * 8 + kt + 1];
            }
            const uint16_t* Ks = Kall + kt * 4096;
            const uint16_t* Vs = Vall + kt * 4096;

            // S = Q K^T
            f32x4 sacc[4];
#pragma unroll
            for (int nf = 0; nf < 4; ++nf) sacc[nf] = (f32x4){0.f, 0.f, 0.f, 0.f};
            __builtin_amdgcn_s_setprio(1);
#pragma unroll
            for (int nf = 0; nf < 4; ++nf)
                sacc[nf] = mfma16(aq0, lds_frag(Ks, nf * 16 + fr, fq * 16), sacc[nf]);
#pragma unroll
            for (int nf = 0; nf < 4; ++nf)
                sacc[nf] = mfma16(aq1, lds_frag(Ks, nf * 16 + fr, 64 + fq * 16), sacc[nf]);
            __builtin_amdgcn_s_setprio(0);

            // mask (scale folded into q)
            float s[4][4];
#pragma unroll
            for (int j = 0; j < 4; ++j) {
                uint64_t m = adjw[kt & 1][j];
#pragma unroll
                for (int nf = 0; nf < 4; ++nf)
                    s[nf][j] = ((m >> (nf * 16 + fr)) & 1) ? sacc[nf][j] : -1e30f;
            }

            // online softmax
            float fsc[4];
#pragma unroll
            for (int j = 0; j < 4; ++j) {
                float t = fmaxf(fmaxf(s[0][j], s[1][j]), fmaxf(s[2][j], s[3][j]));
                t = fmaxf(t, __shfl_xor(t, 1));
                t = fmaxf(t, __shfl_xor(t, 2));
                t = fmaxf(t, __shfl_xor(t, 4));
                t = fmaxf(t, __shfl_xor(t, 8));
                float mn = fmaxf(mrun[j], t);
                fsc[j] = exp2f((mrun[j] - mn) * LOG2E);
                mrun[j] = mn;
            }
            float rs[4] = {0.f, 0.f, 0.f, 0.f};
#pragma unroll
            for (int nf = 0; nf < 4; ++nf)
#pragma unroll
                for (int j = 0; j < 4; ++j) {
                    float p = exp2f((s[nf][j] - mrun[j]) * LOG2E);
                    s[nf][j] = p;
                    rs[j] += p;
                }
#pragma unroll
            for (int j = 0; j < 4; ++j) {
                float r = rs[j];
                r += __shfl_xor(r, 1);
                r += __shfl_xor(r, 2);
                r += __shfl_xor(r, 4);
                r += __shfl_xor(r, 8);
                lsum[j] = lsum[j] * fsc[j] + r;
            }
#pragma unroll
            for (int nf = 0; nf < 4; ++nf)
#pragma unroll
                for (int j = 0; j < 4; ++j) oacc[nf][j] *= fsc[j];

            // P -> per-wave LDS (same-wave read; no barrier)
#pragma unroll
            for (int nf = 0; nf < 4; ++nf)
#pragma unroll
                for (int j = 0; j < 4; ++j) {
                    int rp = fq * 4 + j, cp = nf * 16 + fr;
                    int off = rp * 128 + ((cp * 2) ^ ((rp & 7) << 4));
                    *reinterpret_cast<uint16_t*>(reinterpret_cast<char*>(pw) + off) =
                        f2bf(s[nf][j]);
                }

            // O += P V
            __builtin_amdgcn_s_setprio(1);
#pragma unroll
            for (int ks = 0; ks < 2; ++ks) {
                int kb = ks * 64 + fq * 16;
                bf16x8 ap = lds_frag(pw, fr, kb);
#pragma unroll
                for (int nf = 0; nf < 4; ++nf)
                    oacc[nf] = mfma16(ap, lds_frag(Vs, nf * 16 + fr, kb), oacc[nf]);
            }
            __builtin_amdgcn_s_setprio(0);
        }

        // store strip output [B,N,H,64]
#pragma unroll
        for (int nf = 0; nf < 4; ++nf) {
            int d = nf * 16 + fr;
#pragma unroll
            for (int j = 0; j < 4; ++j) {
                int n = qr0 + fq * 4 + j;
                ows[((size_t)(b * 512 + n) * 8 + h) * 64 + d] = f2bf(oacc[nf][j] / lsum[j]);
            }
        }
        aq0 = aqn0; aq1 = aqn1;
    }
}

// ---------- launch ----------
extern "C" void kernel_launch(void* const* d_in, const int* in_sizes, int n_in,
                              void* d_out, int out_size, void* d_ws, size_t ws_size,
                              hipStream_t stream) {
    const float* x  = (const float*)d_in[0];
    const void*  adj = d_in[1];
    const float* Wq = (const float*)d_in[2];
    const float* Wk = (const float*)d_in[3];
    const float* Wv = (const float*)d_in[4];
    const float* bq = (const float*)d_in[5];
    const float* bk = (const float*)d_in[6];
    const float* bv = (const float*)d_in[7];
    const float* Wo = (const float*)d_in[8];
    const float* bo = (const float*)d_in[9];
    float* out = (float*)d_out;

    char* p = (char*)d_ws;
    uint16_t* ows = (uint16_t*)p; p += (size_t)8388608 * 2;
    uint16_t* wqb = (uint16_t*)p; p += 262144 * 2;
    uint16_t* wkb = (uint16_t*)p; p += 262144 * 2;
    uint16_t* wvb = (uint16_t*)p; p += 262144 * 2;
    uint16_t* wob = (uint16_t*)p; p += 262144 * 2;
    uint16_t* qws = (uint16_t*)p; p += (size_t)8388608 * 2;
    uint16_t* kws = (uint16_t*)p; p += (size_t)8388608 * 2;
    uint16_t* vws = (uint16_t*)p; p += (size_t)8388608 * 2;
    uint64_t* adjbits = (uint64_t*)p; p += 4096 * 8;
    int* flag = (int*)p;

    detect_kernel<<<1, 256, 0, stream>>>((const unsigned int*)adj, flag);
    pack_kernel<<<16, 256, 0, stream>>>(adj, flag, adjbits);
    convert_kernel<<<1024, 256, 0, stream>>>(Wq, Wk, Wv, Wo, wqb, wkb, wvb, wob);
    dim3 g1(12, 128);
    gemm_kernel<0><<<g1, 256, 0, stream>>>(x, nullptr, wqb, wkb, wvb, bq, bk, bv,
                                           qws, kws, vws, nullptr);
    attn_kernel<<<256, 512, 0, stream>>>(qws, kws, vws, adjbits, ows);
    dim3 g2(4, 128);
    gemm_kernel<1><<<g2, 256, 0, stream>>>(nullptr, ows, wob, wob, wob, bo, bo, bo,
                                           nullptr, nullptr, nullptr, out);
}

// Round 16
// 308.398 us; speedup vs baseline: 1.2599x; 1.0250x over previous
//
#include <hip/hip_runtime.h>
#include <stdint.h>

typedef __bf16 bf16_t;
typedef bf16_t bf16x8 __attribute__((ext_vector_type(8)));
typedef float f32x4 __attribute__((ext_vector_type(4)));

// ---------- helpers ----------

__device__ __forceinline__ uint16_t f2bf(float f) {
    uint32_t u = __float_as_uint(f);
    u += 0x7FFFu + ((u >> 16) & 1u);   // RNE
    return (uint16_t)(u >> 16);
}
__device__ __forceinline__ uint32_t pk2bf(float lo, float hi) {
    return (uint32_t)f2bf(lo) | ((uint32_t)f2bf(hi) << 16);
}

__device__ __forceinline__ f32x4 mfma16(bf16x8 a, bf16x8 b, f32x4 c) {
    return __builtin_amdgcn_mfma_f32_16x16x32_bf16(a, b, c, 0, 0, 0);
}

// read one 16B MFMA fragment from a [rows][64] bf16 LDS tile with XOR swizzle
__device__ __forceinline__ bf16x8 lds_frag(const uint16_t* smem, int row, int kbyte) {
    int off = row * 128 + (kbyte ^ ((row & 7) << 4));
    return __builtin_bit_cast(bf16x8,
        *reinterpret_cast<const uint4*>(reinterpret_cast<const char*>(smem) + off));
}

// bf16 tile staging (256 threads): global -> regs, regs -> swizzled LDS
template <int ROWS>
__device__ __forceinline__ void load_regs(uint4* r, const uint16_t* src,
                                          int src_stride, int tid) {
    constexpr int PER = ROWS * 8 / 256;
#pragma unroll
    for (int i = 0; i < PER; ++i) {
        int c = tid + i * 256;
        int row = c >> 3, cc = c & 7;
        r[i] = *reinterpret_cast<const uint4*>(src + (size_t)row * src_stride + cc * 8);
    }
}
template <int ROWS>
__device__ __forceinline__ void write_lds(uint16_t* lds, const uint4* r, int tid) {
    constexpr int PER = ROWS * 8 / 256;
#pragma unroll
    for (int i = 0; i < PER; ++i) {
        int c = tid + i * 256;
        int row = c >> 3, cc = c & 7;
        int off = row * 128 + ((cc * 16) ^ ((row & 7) << 4));
        *reinterpret_cast<uint4*>(reinterpret_cast<char*>(lds) + off) = r[i];
    }
}

// fp32 tile staging for 128-row tile (256 threads): 8 float4 per thread
__device__ __forceinline__ void load_regs_f32(float4* r, const float* src, int tid) {
#pragma unroll
    for (int i = 0; i < 4; ++i) {
        int fc = tid * 2 + i * 512;          // even float4 index
        int row = fc >> 4, cc = fc & 15;
        const float* p = src + (size_t)row * 512 + cc * 4;
        r[2 * i]     = *reinterpret_cast<const float4*>(p);
        r[2 * i + 1] = *reinterpret_cast<const float4*>(p + 4);
    }
}
__device__ __forceinline__ void write_lds_f32(uint16_t* lds, const float4* r, int tid) {
#pragma unroll
    for (int i = 0; i < 4; ++i) {
        int c = tid + i * 256;               // bf16 16B-chunk index
        int row = c >> 3, cc = c & 7;
        uint4 u;
        u.x = pk2bf(r[2 * i].x,     r[2 * i].y);
        u.y = pk2bf(r[2 * i].z,     r[2 * i].w);
        u.z = pk2bf(r[2 * i + 1].x, r[2 * i + 1].y);
        u.w = pk2bf(r[2 * i + 1].z, r[2 * i + 1].w);
        int off = row * 128 + ((cc * 16) ^ ((row & 7) << 4));
        *reinterpret_cast<uint4*>(reinterpret_cast<char*>(lds) + off) = u;
    }
}

// ---------- kernel 0: adj dtype detect ----------
__global__ void detect_kernel(const unsigned int* __restrict__ adj, int* __restrict__ flag) {
    __shared__ int notint, notf32;
    if (threadIdx.x == 0) { notint = 0; notf32 = 0; }
    __syncthreads();
    int ni = 0, nf = 0;
    for (int i = threadIdx.x; i < 4096; i += 256) {
        unsigned v = adj[i];
        if (v > 1u) ni = 1;
        if (v != 0u && v != 0x3f800000u) nf = 1;
    }
    if (ni) notint = 1;
    if (nf) notf32 = 1;
    __syncthreads();
    if (threadIdx.x == 0) *flag = notint ? (notf32 ? 2 : 1) : 0;
}

// ---------- kernel 0b: pack adj into bitmask [512 rows][8 x uint64] ----------
__global__ void pack_kernel(const void* __restrict__ adj, const int* __restrict__ flag,
                            uint64_t* __restrict__ bits) {
    int idx = blockIdx.x * 256 + threadIdx.x;   // 4096 words
    int row = idx >> 3, w = idx & 7;
    int mode = *flag;
    uint64_t m = 0;
    if (mode == 0) {
        const int* a = (const int*)adj + row * 512 + w * 64;
#pragma unroll 8
        for (int b = 0; b < 64; ++b) m |= (uint64_t)(a[b] != 0) << b;
    } else if (mode == 1) {
        const float* a = (const float*)adj + row * 512 + w * 64;
#pragma unroll 8
        for (int b = 0; b < 64; ++b) m |= (uint64_t)(a[b] != 0.0f) << b;
    } else {
        const unsigned char* a = (const unsigned char*)adj + row * 512 + w * 64;
#pragma unroll 8
        for (int b = 0; b < 64; ++b) m |= (uint64_t)(a[b] != 0) << b;
    }
    bits[idx] = m;
}

// ---------- kernel 1: fp32 -> bf16 convert (weights only now) ----------
__global__ void convert_kernel(const float* __restrict__ wq, const float* __restrict__ wk,
                               const float* __restrict__ wv, const float* __restrict__ wo,
                               uint16_t* __restrict__ wqb, uint16_t* __restrict__ wkb,
                               uint16_t* __restrict__ wvb, uint16_t* __restrict__ wob) {
    int i = blockIdx.x * 256 + threadIdx.x;   // float4 index over 4*65536
    int which = i >> 16, idx = i & 65535;
    const float* src = which == 0 ? wq : which == 1 ? wk : which == 2 ? wv : wo;
    uint16_t*    dst = which == 0 ? wqb : which == 1 ? wkb : which == 2 ? wvb : wob;
    float4 v = reinterpret_cast<const float4*>(src)[idx];
    ushort4 o;
    o.x = f2bf(v.x); o.y = f2bf(v.y); o.z = f2bf(v.z); o.w = f2bf(v.w);
    reinterpret_cast<ushort4*>(dst)[idx] = o;
}

// ---------- GEMM template (2-phase reg-prefetch + LDS-transpose epilogue) ----------
// 1D grid, XCD-grouped remap: g = id & 127 (m-group), j = id >> 7 (n-block).
// Blocks sharing an A-tile (same g) sit at dispatch ids {g, 128+g, ...} == g (mod 8)
// -> same XCD -> A-tile lands in that XCD's L2 once and is reused by all n-blocks.
// MODE 0: A = x fp32 (convert in staging); writes q (pre-scaled 1/8), k [B,H,N,64], v^T [B,H,64,N]
// MODE 1: A = bf16 (attn out); writes fp32 [M][512] + bias
template <int MODE>
__launch_bounds__(256)
__global__ void gemm_kernel(const float* __restrict__ Af, const uint16_t* __restrict__ Ab,
                            const uint16_t* __restrict__ B0, const uint16_t* __restrict__ B1,
                            const uint16_t* __restrict__ B2,
                            const float* __restrict__ bias0, const float* __restrict__ bias1,
                            const float* __restrict__ bias2,
                            uint16_t* __restrict__ qws, uint16_t* __restrict__ kws,
                            uint16_t* __restrict__ vws, float* __restrict__ outf) {
    __shared__ uint16_t smem[128 * 128];     // K-loop: As|Bs; epilogue: 128x128 C tile
    uint16_t* As = smem;
    uint16_t* Bs = smem + 128 * 64;
    const int tid  = threadIdx.x;
    const int lane = tid & 63;
    const int wid  = tid >> 6;
    const int wm   = wid >> 1, wn = wid & 1;
    const int gid  = blockIdx.x;
    const int m0   = (gid & 127) * 128;      // XCD-grouped: same-A blocks -> same XCD
    const int n0   = (gid >> 7) * 128;
    const int sel  = n0 >> 9;
    const int nw   = n0 & 511;
    const uint16_t* Bsrc = (MODE == 0) ? (sel == 0 ? B0 : sel == 1 ? B1 : B2) : B0;
    const int fr = lane & 15, fq = lane >> 4;

    f32x4 acc[4][4];
#pragma unroll
    for (int a = 0; a < 4; ++a)
#pragma unroll
        for (int b = 0; b < 4; ++b) acc[a][b] = (f32x4){0.f, 0.f, 0.f, 0.f};

    float4 apre_f[8];
    uint4  apre_b[4];
    uint4  bpre[4];
    if (MODE == 0) load_regs_f32(apre_f, Af + (size_t)m0 * 512, tid);
    else           load_regs<128>(apre_b, Ab + (size_t)m0 * 512, 512, tid);
    load_regs<128>(bpre, Bsrc + (size_t)nw * 512, 512, tid);

    for (int k0 = 0; k0 < 512; k0 += 64) {
        __syncthreads();
        if (MODE == 0) write_lds_f32(As, apre_f, tid);
        else           write_lds<128>(As, apre_b, tid);
        write_lds<128>(Bs, bpre, tid);
        if (k0 < 448) {
            if (MODE == 0) load_regs_f32(apre_f, Af + (size_t)m0 * 512 + k0 + 64, tid);
            else           load_regs<128>(apre_b, Ab + (size_t)m0 * 512 + k0 + 64, 512, tid);
            load_regs<128>(bpre, Bsrc + (size_t)nw * 512 + k0 + 64, 512, tid);
        }
        __syncthreads();
#pragma unroll
        for (int ks = 0; ks < 2; ++ks) {
            int kb = ks * 64 + fq * 16;
            bf16x8 af[4], bfr[4];
#pragma unroll
            for (int i = 0; i < 4; ++i) af[i]  = lds_frag(As, wm * 64 + i * 16 + fr, kb);
#pragma unroll
            for (int i = 0; i < 4; ++i) bfr[i] = lds_frag(Bs, wn * 64 + i * 16 + fr, kb);
#pragma unroll
            for (int mf = 0; mf < 4; ++mf)
#pragma unroll
                for (int nf = 0; nf < 4; ++nf)
                    acc[mf][nf] = mfma16(af[mf], bfr[nf], acc[mf][nf]);
        }
    }

    if (MODE == 0) {
        const float* bias = sel == 0 ? bias0 : sel == 1 ? bias1 : bias2;
        const float sc = (sel == 0) ? 0.125f : 1.0f;   // fold 1/sqrt(DH) into q
        const int b  = m0 >> 9;
        const int ns = m0 & 511;
        const int h0 = nw >> 6;
        char* sm = reinterpret_cast<char*>(smem);
        __syncthreads();

        if (sel < 2) {
            // acc -> LDS [m][c] bf16 swizzled, b32-packed
#pragma unroll
            for (int nf = 0; nf < 4; ++nf) {
                int c = wn * 64 + nf * 16 + fr;
                float bv = bias[nw + c];
#pragma unroll
                for (int mf = 0; mf < 4; ++mf) {
#pragma unroll
                    for (int j = 0; j < 4; ++j) {
                        int m = wm * 64 + mf * 16 + fq * 4 + j;
                        uint32_t u = f2bf((acc[mf][nf][j] + bv) * sc);
                        uint32_t partner = __shfl_xor((int)u, 1);
                        if ((fr & 1) == 0) {
                            uint32_t word = u | (partner << 16);
                            int off = m * 256 + (((c & ~1) * 2) ^ ((m & 7) << 4));
                            *reinterpret_cast<uint32_t*>(sm + off) = word;
                        }
                    }
                }
            }
            __syncthreads();
            uint16_t* dst = (sel == 0) ? qws : kws;
#pragma unroll
            for (int pass = 0; pass < 8; ++pass) {
                int idx = pass * 256 + tid;
                int m = idx >> 4, cchunk = idx & 15;
                int off = m * 256 + ((cchunk * 16) ^ ((m & 7) << 4));
                uint4 v = *reinterpret_cast<const uint4*>(sm + off);
                int h = h0 + (cchunk >> 3), dh = (cchunk & 7) * 8;
                *reinterpret_cast<uint4*>(
                    dst + ((size_t)((b * 8 + h) * 512) + ns + m) * 64 + dh) = v;
            }
        } else {
            // acc -> LDS transposed [c][m] bf16 swizzled, 8B-packed
#pragma unroll
            for (int nf = 0; nf < 4; ++nf) {
                int c = wn * 64 + nf * 16 + fr;
                float bv = bias[nw + c];
#pragma unroll
                for (int mf = 0; mf < 4; ++mf) {
                    int m = wm * 64 + mf * 16 + fq * 4;
                    uint64_t pk = (uint64_t)f2bf(acc[mf][nf][0] + bv) |
                                  ((uint64_t)f2bf(acc[mf][nf][1] + bv) << 16) |
                                  ((uint64_t)f2bf(acc[mf][nf][2] + bv) << 32) |
                                  ((uint64_t)f2bf(acc[mf][nf][3] + bv) << 48);
                    int off = c * 256 + ((m * 2) ^ ((c & 7) << 4));
                    *reinterpret_cast<uint64_t*>(sm + off) = pk;
                }
            }
            __syncthreads();
#pragma unroll
            for (int pass = 0; pass < 8; ++pass) {
                int idx = pass * 256 + tid;
                int c = idx >> 4, mchunk = idx & 15;
                int off = c * 256 + ((mchunk * 16) ^ ((c & 7) << 4));
                uint4 v = *reinterpret_cast<const uint4*>(sm + off);
                int h = h0 + (c >> 6), dh = c & 63;
                *reinterpret_cast<uint4*>(
                    vws + ((size_t)((b * 8 + h) * 64) + dh) * 512 + ns + mchunk * 8) = v;
            }
        }
    } else {
#pragma unroll
        for (int nf = 0; nf < 4; ++nf) {
            int c = n0 + wn * 64 + nf * 16 + fr;
            float bv = bias0[c];
#pragma unroll
            for (int mf = 0; mf < 4; ++mf) {
                int mbase = m0 + wm * 64 + mf * 16 + fq * 4;
#pragma unroll
                for (int j = 0; j < 4; ++j)
                    outf[(size_t)(mbase + j) * 512 + c] = acc[mf][nf][j] + bv;
            }
        }
    }
}

// ---------- kernel 3: masked flash attention, whole head per block ----------
// grid: B*H = 256 blocks; 512 threads; K + V^T resident in LDS (144 KB)
__launch_bounds__(512)
__global__ void attn_kernel(const uint16_t* __restrict__ qws, const uint16_t* __restrict__ kws,
                            const uint16_t* __restrict__ vws,
                            const uint64_t* __restrict__ adjbits, uint16_t* __restrict__ ows) {
    __shared__ uint16_t Kall[8 * 64 * 64];   // 8 kv-subtiles, swizzled [64][64]
    __shared__ uint16_t Vall[8 * 64 * 64];   // V^T: rows=d, cols=kv, per subtile
    __shared__ uint16_t Ps[8 * 16 * 64];     // per-wave P tile
    const int tid = threadIdx.x, lane = tid & 63, w = tid >> 6;
    const int bx = blockIdx.x;               // b*8 + h
    const int h = bx & 7, b = bx >> 3;
    const size_t qk_head = (size_t)bx * 512 * 64;
    const size_t v_head  = (size_t)bx * 64 * 512;
    const int fr = lane & 15, fq = lane >> 4;
    const float LOG2E = 1.4426950408889634f;

    // ---- stage all K, V^T for this head (128 KB), single barrier ----
    {
        int r = tid >> 3, cc = tid & 7;
        uint4 kr[8], vr[8];
#pragma unroll
        for (int kt = 0; kt < 8; ++kt)
            kr[kt] = *reinterpret_cast<const uint4*>(
                kws + qk_head + (size_t)(kt * 64 + r) * 64 + cc * 8);
#pragma unroll
        for (int kt = 0; kt < 8; ++kt)
            vr[kt] = *reinterpret_cast<const uint4*>(
                vws + v_head + (size_t)r * 512 + kt * 64 + cc * 8);
        int off = r * 128 + ((cc * 16) ^ ((r & 7) << 4));
#pragma unroll
        for (int kt = 0; kt < 8; ++kt) {
            *reinterpret_cast<uint4*>(reinterpret_cast<char*>(Kall + kt * 4096) + off) = kr[kt];
            *reinterpret_cast<uint4*>(reinterpret_cast<char*>(Vall + kt * 4096) + off) = vr[kt];
        }
    }

    // Q fragments for strip 0 (issued before barrier to overlap)
    bf16x8 aq0, aq1, aqn0, aqn1;
    {
        int qr0 = w * 16;
        aq0 = __builtin_bit_cast(bf16x8, *reinterpret_cast<const uint4*>(
            qws + qk_head + (size_t)(qr0 + fr) * 64 + fq * 8));
        aq1 = __builtin_bit_cast(bf16x8, *reinterpret_cast<const uint4*>(
            qws + qk_head + (size_t)(qr0 + fr) * 64 + 32 + fq * 8));
    }
    __syncthreads();   // K/V visible; no further barriers — waves independent

    uint16_t* pw = Ps + w * 16 * 64;

    for (int it = 0; it < 4; ++it) {
        const int qr0 = it * 128 + w * 16;
        const int itn = (it + 1) & 3;
        const int qrn = itn * 128 + w * 16;
        // prefetch next strip's Q (wraps at it=3; harmless)
        aqn0 = __builtin_bit_cast(bf16x8, *reinterpret_cast<const uint4*>(
            qws + qk_head + (size_t)(qrn + fr) * 64 + fq * 8));
        aqn1 = __builtin_bit_cast(bf16x8, *reinterpret_cast<const uint4*>(
            qws + qk_head + (size_t)(qrn + fr) * 64 + 32 + fq * 8));

        // adj words, double-buffered over kt
        uint64_t adjw[2][4];
#pragma unroll
        for (int j = 0; j < 4; ++j)
            adjw[0][j] = adjbits[(size_t)(qr0 + fq * 4 + j) * 8 + 0];

        float mrun[4], lsum[4];
        f32x4 oacc[4];
#pragma unroll
        for (int j = 0; j < 4; ++j) { mrun[j] = -1e30f; lsum[j] = 0.f; }
#pragma unroll
        for (int nf = 0; nf < 4; ++nf) oacc[nf] = (f32x4){0.f, 0.f, 0.f, 0.f};

#pragma unroll
        for (int kt = 0; kt < 8; ++kt) {
            if (kt < 7) {
#pragma unroll
                for (int j = 0; j < 4; ++j)
                    adjw[(kt + 1) & 1][j] = adjbits[(size_t)(qr0 + fq * 4 + j) * 8 + kt + 1];
            }
            const uint16_t* Ks = Kall + kt * 4096;
            const uint16_t* Vs = Vall + kt * 4096;

            // S = Q K^T
            f32x4 sacc[4];
#pragma unroll
            for (int nf = 0; nf < 4; ++nf) sacc[nf] = (f32x4){0.f, 0.f, 0.f, 0.f};
            __builtin_amdgcn_s_setprio(1);
#pragma unroll
            for (int nf = 0; nf < 4; ++nf)
                sacc[nf] = mfma16(aq0, lds_frag(Ks, nf * 16 + fr, fq * 16), sacc[nf]);
#pragma unroll
            for (int nf = 0; nf < 4; ++nf)
                sacc[nf] = mfma16(aq1, lds_frag(Ks, nf * 16 + fr, 64 + fq * 16), sacc[nf]);
            __builtin_amdgcn_s_setprio(0);

            // mask (scale folded into q)
            float s[4][4];
#pragma unroll
            for (int j = 0; j < 4; ++j) {
                uint64_t m = adjw[kt & 1][j];
#pragma unroll
                for (int nf = 0; nf < 4; ++nf)
                    s[nf][j] = ((m >> (nf * 16 + fr)) & 1) ? sacc[nf][j] : -1e30f;
            }

            // online softmax
            float fsc[4];
#pragma unroll
            for (int j = 0; j < 4; ++j) {
                float t = fmaxf(fmaxf(s[0][j], s[1][j]), fmaxf(s[2][j], s[3][j]));
                t = fmaxf(t, __shfl_xor(t, 1));
                t = fmaxf(t, __shfl_xor(t, 2));
                t = fmaxf(t, __shfl_xor(t, 4));
                t = fmaxf(t, __shfl_xor(t, 8));
                float mn = fmaxf(mrun[j], t);
                fsc[j] = exp2f((mrun[j] - mn) * LOG2E);
                mrun[j] = mn;
            }
            float rs[4] = {0.f, 0.f, 0.f, 0.f};
#pragma unroll
            for (int nf = 0; nf < 4; ++nf)
#pragma unroll
                for (int j = 0; j < 4; ++j) {
                    float p = exp2f((s[nf][j] - mrun[j]) * LOG2E);
                    s[nf][j] = p;
                    rs[j] += p;
                }
#pragma unroll
            for (int j = 0; j < 4; ++j) {
                float r = rs[j];
                r += __shfl_xor(r, 1);
                r += __shfl_xor(r, 2);
                r += __shfl_xor(r, 4);
                r += __shfl_xor(r, 8);
                lsum[j] = lsum[j] * fsc[j] + r;
            }
#pragma unroll
            for (int nf = 0; nf < 4; ++nf)
#pragma unroll
                for (int j = 0; j < 4; ++j) oacc[nf][j] *= fsc[j];

            // P -> per-wave LDS (same-wave read; no barrier)
#pragma unroll
            for (int nf = 0; nf < 4; ++nf)
#pragma unroll
                for (int j = 0; j < 4; ++j) {
                    int rp = fq * 4 + j, cp = nf * 16 + fr;
                    int off = rp * 128 + ((cp * 2) ^ ((rp & 7) << 4));
                    *reinterpret_cast<uint16_t*>(reinterpret_cast<char*>(pw) + off) =
                        f2bf(s[nf][j]);
                }

            // O += P V
            __builtin_amdgcn_s_setprio(1);
#pragma unroll
            for (int ks = 0; ks < 2; ++ks) {
                int kb = ks * 64 + fq * 16;
                bf16x8 ap = lds_frag(pw, fr, kb);
#pragma unroll
                for (int nf = 0; nf < 4; ++nf)
                    oacc[nf] = mfma16(ap, lds_frag(Vs, nf * 16 + fr, kb), oacc[nf]);
            }
            __builtin_amdgcn_s_setprio(0);
        }

        // store strip output [B,N,H,64]
#pragma unroll
        for (int nf = 0; nf < 4; ++nf) {
            int d = nf * 16 + fr;
#pragma unroll
            for (int j = 0; j < 4; ++j) {
                int n = qr0 + fq * 4 + j;
                ows[((size_t)(b * 512 + n) * 8 + h) * 64 + d] = f2bf(oacc[nf][j] / lsum[j]);
            }
        }
        aq0 = aqn0; aq1 = aqn1;
    }
}

// ---------- launch ----------
extern "C" void kernel_launch(void* const* d_in, const int* in_sizes, int n_in,
                              void* d_out, int out_size, void* d_ws, size_t ws_size,
                              hipStream_t stream) {
    const float* x  = (const float*)d_in[0];
    const void*  adj = d_in[1];
    const float* Wq = (const float*)d_in[2];
    const float* Wk = (const float*)d_in[3];
    const float* Wv = (const float*)d_in[4];
    const float* bq = (const float*)d_in[5];
    const float* bk = (const float*)d_in[6];
    const float* bv = (const float*)d_in[7];
    const float* Wo = (const float*)d_in[8];
    const float* bo = (const float*)d_in[9];
    float* out = (float*)d_out;

    char* p = (char*)d_ws;
    uint16_t* ows = (uint16_t*)p; p += (size_t)8388608 * 2;
    uint16_t* wqb = (uint16_t*)p; p += 262144 * 2;
    uint16_t* wkb = (uint16_t*)p; p += 262144 * 2;
    uint16_t* wvb = (uint16_t*)p; p += 262144 * 2;
    uint16_t* wob = (uint16_t*)p; p += 262144 * 2;
    uint16_t* qws = (uint16_t*)p; p += (size_t)8388608 * 2;
    uint16_t* kws = (uint16_t*)p; p += (size_t)8388608 * 2;
    uint16_t* vws = (uint16_t*)p; p += (size_t)8388608 * 2;
    uint64_t* adjbits = (uint64_t*)p; p += 4096 * 8;
    int* flag = (int*)p;

    detect_kernel<<<1, 256, 0, stream>>>((const unsigned int*)adj, flag);
    pack_kernel<<<16, 256, 0, stream>>>(adj, flag, adjbits);
    convert_kernel<<<1024, 256, 0, stream>>>(Wq, Wk, Wv, Wo, wqb, wkb, wvb, wob);
    gemm_kernel<0><<<1536, 256, 0, stream>>>(x, nullptr, wqb, wkb, wvb, bq, bk, bv,
                                             qws, kws, vws, nullptr);
    attn_kernel<<<256, 512, 0, stream>>>(qws, kws, vws, adjbits, ows);
    gemm_kernel<1><<<512, 256, 0, stream>>>(nullptr, ows, wob, wob, wob, bo, bo, bo,
                                            nullptr, nullptr, nullptr, out);
}